// Round 1
// baseline (5430.490 us; speedup 1.0000x reference)
//
#include <hip/hip_runtime.h>

// CRF forward algorithm on MI355X.
// Strategy: linear-domain recurrence v_{t} = diag(2^feat) * (E @ v_{t-1}) with
// E = exp(transitions[1:,:]) held entirely in VGPRs across 256 persistent
// blocks (256 regs/thread * 64k threads == the 67MB matrix). Per step only the
// 4096-float state crosses blocks, synchronized by NaN-sentinel polling on an
// 8-slot ring (agent-scope loads/stores to bypass non-coherent per-XCD L2).

#define T_STEPS 1024
#define NRULES  4095
#define NTAGS   4096
#define RING    8
#define L2E     1.4426950408889634f
#define LN2     0.69314718055994530942

__device__ __forceinline__ float ld_agent(const float* p) {
  return __hip_atomic_load(p, __ATOMIC_RELAXED, __HIP_MEMORY_SCOPE_AGENT);
}
__device__ __forceinline__ void st_agent(float* p, float v) {
  __hip_atomic_store(p, v, __ATOMIC_RELAXED, __HIP_MEMORY_SCOPE_AGENT);
}

// Ring init: slot 0 = p_0 = [1, 0, 0, ...] (START state), slots 1..7 = NaN.
__global__ void crf_init(float* __restrict__ pring) {
  const float NANF = __builtin_nanf("");
  int idx = blockIdx.x * blockDim.x + threadIdx.x;
  int stride = gridDim.x * blockDim.x;
  for (int i = idx; i < RING * NTAGS; i += stride) {
    int slot = i >> 12;
    float v = (slot == 0) ? ((i == 0) ? 1.0f : 0.0f) : NANF;
    st_agent(&pring[i], v);
  }
}

// Supervised path: sum of emit + transition scores along the given tag path.
__global__ void crf_logprob(const float* __restrict__ feats,
                            const float* __restrict__ trans,
                            const int* __restrict__ tags,
                            float* __restrict__ lp) {
  int t = threadIdx.x;  // 1024 threads, one per step
  int prev = (t == 0) ? 0 : tags[t - 1];
  int nxt  = tags[t];
  int er = prev - 1; if (er < 0) er += NRULES;   // (prev-1) mod NRULES, Python semantics
  float v = feats[(size_t)t * NRULES + er] + trans[(size_t)nxt * NTAGS + prev];
  #pragma unroll
  for (int d = 32; d; d >>= 1) v += __shfl_xor(v, d, 64);
  __shared__ float sb[16];
  if ((t & 63) == 0) sb[t >> 6] = v;
  __syncthreads();
  if (t == 0) {
    float s = 0.f;
    #pragma unroll
    for (int i = 0; i < 16; ++i) s += sb[i];
    lp[0] = s;
  }
}

// Persistent scan. Grid 256 x block 256. Wave w of block g owns tags
// [g*16 + 4w, g*16 + 4w + 4); lane l owns columns [64l, 64l+64).
// tag 0 (START) is a dummy row with E=0 -> s=0 -> y=-inf -> p=0 forever.
__launch_bounds__(256, 1)
__global__ void crf_scan(const float* __restrict__ feats,
                         const float* __restrict__ trans,
                         float* __restrict__ pring,
                         const float* __restrict__ lp,
                         float* __restrict__ out)
{
  const int g    = blockIdx.x;
  const int tid  = threadIdx.x;
  const int wave = tid >> 6;
  const int lane = tid & 63;
  const int tagbase = g * 16 + wave * 4;

  // p staged with +4 floats of pad per 64 so each lane's 64-float run starts
  // at float index 68*lane (byte 272*lane, 16B aligned, banks spread).
  __shared__ __align__(16) float stage[4352];
  __shared__ float wmax[4];
  __shared__ int giveup;

  // ---- one-time: E[r][c] = exp(transitions[tag][64*lane + c]) in VGPRs ----
  float E[4][64];
  #pragma unroll
  for (int r = 0; r < 4; ++r) {
    const int tag = tagbase + r;
    if (tag == 0) {
      #pragma unroll
      for (int c = 0; c < 64; ++c) E[r][c] = 0.0f;
    } else {
      const float* row = trans + (size_t)tag * NTAGS + lane * 64;
      #pragma unroll
      for (int c = 0; c < 64; c += 4) {
        float4 v = *reinterpret_cast<const float4*>(row + c);
        E[r][c + 0] = __builtin_amdgcn_exp2f(v.x * L2E);
        E[r][c + 1] = __builtin_amdgcn_exp2f(v.y * L2E);
        E[r][c + 2] = __builtin_amdgcn_exp2f(v.z * L2E);
        E[r][c + 3] = __builtin_amdgcn_exp2f(v.w * L2E);
      }
    }
  }

  if (tid == 0) giveup = 0;

  double Racc = 0.0;  // running log2-offset sum; identical on all threads

  for (int t = 1; t <= T_STEPS; ++t) {
    const int sprev = (t - 1) & (RING - 1);
    const int scur  = t & (RING - 1);
    const float* pprev = pring + sprev * NTAGS;

    __syncthreads();            // stage reusable; giveup visible

    if (giveup) break;

    // ---- poll + load p_{t-1}: values ARE the flags (NaN = not yet written)
    float pv[16];
    #pragma unroll
    for (int i = 0; i < 16; ++i) pv[i] = ld_agent(&pprev[tid + 256 * i]);
    {
      int rounds = 0;
      for (;;) {
        bool bad = false;
        #pragma unroll
        for (int i = 0; i < 16; ++i) bad |= (pv[i] != pv[i]);
        if (__ballot(bad) == 0ull) break;
        if (++rounds > (1 << 18)) { giveup = 1; break; }  // fail loud, not hang
        __builtin_amdgcn_s_sleep(1);
        #pragma unroll
        for (int i = 0; i < 16; ++i)
          if (pv[i] != pv[i]) pv[i] = ld_agent(&pprev[tid + 256 * i]);
      }
    }

    // ---- recycle slot t-2 to NaN. Safe: seeing full p_{t-1} implies every
    // wave passed its step-(t-1) poll of slot t-2 (skew <= 1 step).
    if (t >= 2 && wave == 0 && lane < 16)
      st_agent(&pring[((t - 2) & (RING - 1)) * NTAGS + g * 16 + lane],
               __builtin_nanf(""));

    // ---- stage p into LDS, track block max (= 2^(M_{t-1} - M_{t-2}))
    float mloc = 0.0f;  // p >= 0
    #pragma unroll
    for (int i = 0; i < 16; ++i) {
      const int f = tid + 256 * i;
      stage[f + 4 * (f >> 6)] = pv[i];
      mloc = fmaxf(mloc, pv[i]);
    }
    #pragma unroll
    for (int d = 32; d; d >>= 1) mloc = fmaxf(mloc, __shfl_xor(mloc, d, 64));
    if (lane == 0) wmax[wave] = mloc;

    // feats for my 4 rows (read-only input, normal cached loads)
    float fe[4];
    #pragma unroll
    for (int r = 0; r < 4; ++r) {
      const int tag = tagbase + r;
      const int fi = (tag == 0) ? 0 : tag - 1;
      fe[r] = feats[(size_t)(t - 1) * NRULES + fi] * L2E;
    }

    __syncthreads();

    if (giveup) break;

    const float pmax  = fmaxf(fmaxf(wmax[0], wmax[1]), fmaxf(wmax[2], wmax[3]));
    const float rprev = __builtin_amdgcn_logf(pmax);   // log2(max p_{t-1})
    Racc += (double)rprev;

    // ---- matvec: a_r = sum_j E[r][j] * p[j] over this lane's 64 columns
    float a0 = 0.f, a1 = 0.f, a2 = 0.f, a3 = 0.f;
    const float* myp = stage + 68 * lane;
    #pragma unroll
    for (int k = 0; k < 16; ++k) {
      const float4 q = *reinterpret_cast<const float4*>(myp + 4 * k);
      a0 += E[0][4*k+0]*q.x; a1 += E[1][4*k+0]*q.x; a2 += E[2][4*k+0]*q.x; a3 += E[3][4*k+0]*q.x;
      a0 += E[0][4*k+1]*q.y; a1 += E[1][4*k+1]*q.y; a2 += E[2][4*k+1]*q.y; a3 += E[3][4*k+1]*q.y;
      a0 += E[0][4*k+2]*q.z; a1 += E[1][4*k+2]*q.z; a2 += E[2][4*k+2]*q.z; a3 += E[3][4*k+2]*q.z;
      a0 += E[0][4*k+3]*q.w; a1 += E[1][4*k+3]*q.w; a2 += E[2][4*k+3]*q.w; a3 += E[3][4*k+3]*q.w;
    }
    #pragma unroll
    for (int d = 32; d; d >>= 1) {
      a0 += __shfl_xor(a0, d, 64);
      a1 += __shfl_xor(a1, d, 64);
      a2 += __shfl_xor(a2, d, 64);
      a3 += __shfl_xor(a3, d, 64);
    }

    // y = acc_t - M_{t-1} in log2 domain; publish p_t = 2^y
    const float y0 = fe[0] + __builtin_amdgcn_logf(a0) - rprev;
    const float y1 = fe[1] + __builtin_amdgcn_logf(a1) - rprev;
    const float y2 = fe[2] + __builtin_amdgcn_logf(a2) - rprev;
    const float y3 = fe[3] + __builtin_amdgcn_logf(a3) - rprev;

    if (lane < 4) {
      const float y = (lane == 0) ? y0 : (lane == 1) ? y1 : (lane == 2) ? y2 : y3;
      st_agent(&pring[scur * NTAGS + tagbase + lane], __builtin_amdgcn_exp2f(y));
    }
  }

  // ---- finalization: Z = ln2 * (log2(sum p_T) + M_{T-1}); out = Z - logprob
  if (g == 0) {
    const float* pT = pring + (T_STEPS & (RING - 1)) * NTAGS;
    float pv[16];
    #pragma unroll
    for (int i = 0; i < 16; ++i) pv[i] = ld_agent(&pT[tid + 256 * i]);
    {
      int rounds = 0;
      for (;;) {
        bool bad = false;
        #pragma unroll
        for (int i = 0; i < 16; ++i) bad |= (pv[i] != pv[i]);
        if (__ballot(bad) == 0ull) break;
        if (++rounds > (1 << 18)) break;
        __builtin_amdgcn_s_sleep(1);
        #pragma unroll
        for (int i = 0; i < 16; ++i)
          if (pv[i] != pv[i]) pv[i] = ld_agent(&pT[tid + 256 * i]);
      }
    }
    float s = 0.f;
    #pragma unroll
    for (int i = 0; i < 16; ++i) s += pv[i];
    #pragma unroll
    for (int d = 32; d; d >>= 1) s += __shfl_xor(s, d, 64);
    __syncthreads();
    if (lane == 0) wmax[wave] = s;
    __syncthreads();
    if (tid == 0) {
      const float tot = wmax[0] + wmax[1] + wmax[2] + wmax[3];
      const double Z2 = (double)__builtin_amdgcn_logf(tot) + Racc;
      out[0] = (float)(LN2 * Z2 - (double)lp[0]);
    }
  }
}

extern "C" void kernel_launch(void* const* d_in, const int* in_sizes, int n_in,
                              void* d_out, int out_size, void* d_ws, size_t ws_size,
                              hipStream_t stream) {
  const float* feats = (const float*)d_in[0];   // (1024, 1, 4095) f32
  const float* trans = (const float*)d_in[1];   // (4096, 4096) f32
  const int*   tags  = (const int*)d_in[2];     // (1024,) i32
  float* out   = (float*)d_out;                 // (1,) f32
  float* pring = (float*)d_ws;                  // RING * NTAGS floats
  float* lp    = pring + RING * NTAGS;          // 1 float

  crf_init<<<64, 256, 0, stream>>>(pring);
  crf_logprob<<<1, 1024, 0, stream>>>(feats, trans, tags, lp);
  crf_scan<<<256, 256, 0, stream>>>(feats, trans, pring, lp, out);
}

// Round 2
// 4898.359 us; speedup vs baseline: 1.1086x; 1.1086x over previous
//
#include <hip/hip_runtime.h>

// CRF forward algorithm on MI355X.
// Linear-domain recurrence v_t = diag(2^feat) * (E @ v_{t-1}) with
// E = exp(transitions) held in VGPRs across 256 persistent blocks.
// Round 2 change: 512 threads/block, E[2][64] = 128 floats/thread
// (round 1's E[4][64]=256 floats spilled to scratch: VGPR_Count=176,
// FETCH_SIZE 256MB -> per-step L3 reload dominated at ~5 ms).
// Per step only the 4096-float state crosses blocks, synchronized by
// NaN-sentinel polling on an 8-slot ring (agent-scope ld/st).

#define T_STEPS 1024
#define NRULES  4095
#define NTAGS   4096
#define RING    8
#define L2E     1.4426950408889634f
#define LN2     0.69314718055994530942

__device__ __forceinline__ float ld_agent(const float* p) {
  return __hip_atomic_load(p, __ATOMIC_RELAXED, __HIP_MEMORY_SCOPE_AGENT);
}
__device__ __forceinline__ void st_agent(float* p, float v) {
  __hip_atomic_store(p, v, __ATOMIC_RELAXED, __HIP_MEMORY_SCOPE_AGENT);
}

// Ring init: slot 0 = p_0 = [1, 0, 0, ...] (START state), slots 1..7 = NaN.
__global__ void crf_init(float* __restrict__ pring) {
  const float NANF = __builtin_nanf("");
  int idx = blockIdx.x * blockDim.x + threadIdx.x;
  int stride = gridDim.x * blockDim.x;
  for (int i = idx; i < RING * NTAGS; i += stride) {
    int slot = i >> 12;
    float v = (slot == 0) ? ((i == 0) ? 1.0f : 0.0f) : NANF;
    st_agent(&pring[i], v);
  }
}

// Supervised path: sum of emit + transition scores along the given tag path.
__global__ void crf_logprob(const float* __restrict__ feats,
                            const float* __restrict__ trans,
                            const int* __restrict__ tags,
                            float* __restrict__ lp) {
  int t = threadIdx.x;  // 1024 threads, one per step
  int prev = (t == 0) ? 0 : tags[t - 1];
  int nxt  = tags[t];
  int er = prev - 1; if (er < 0) er += NRULES;   // (prev-1) mod NRULES
  float v = feats[(size_t)t * NRULES + er] + trans[(size_t)nxt * NTAGS + prev];
  #pragma unroll
  for (int d = 32; d; d >>= 1) v += __shfl_xor(v, d, 64);
  __shared__ float sb[16];
  if ((t & 63) == 0) sb[t >> 6] = v;
  __syncthreads();
  if (t == 0) {
    float s = 0.f;
    #pragma unroll
    for (int i = 0; i < 16; ++i) s += sb[i];
    lp[0] = s;
  }
}

// Persistent scan. Grid 256 x block 512 (8 waves). Wave w of block g owns
// tags [g*16 + 2w, g*16 + 2w + 2); lane l owns columns [64l, 64l+64).
// tag 0 (START) is a dummy row with E=0 -> s=0 -> p=0 forever.
__launch_bounds__(512, 2)
__global__ void crf_scan(const float* __restrict__ feats,
                         const float* __restrict__ trans,
                         float* __restrict__ pring,
                         const float* __restrict__ lp,
                         float* __restrict__ out)
{
  const int g    = blockIdx.x;
  const int tid  = threadIdx.x;
  const int wave = tid >> 6;
  const int lane = tid & 63;
  const int tagbase = g * 16 + wave * 2;

  // p staged with +4 floats of pad per 64 so each lane's 64-float run starts
  // at float index 68*lane (byte 272*lane, 16B aligned, banks spread).
  __shared__ __align__(16) float stage[4352];
  __shared__ float wmax[8];
  __shared__ int giveup;

  // ---- one-time: E[r][c] = exp(transitions[tag][64*lane + c]) in VGPRs ----
  float E[2][64];
  #pragma unroll
  for (int r = 0; r < 2; ++r) {
    const int tag = tagbase + r;
    if (tag == 0) {
      #pragma unroll
      for (int c = 0; c < 64; ++c) E[r][c] = 0.0f;
    } else {
      const float* row = trans + (size_t)tag * NTAGS + lane * 64;
      #pragma unroll
      for (int c = 0; c < 64; c += 4) {
        float4 v = *reinterpret_cast<const float4*>(row + c);
        E[r][c + 0] = __builtin_amdgcn_exp2f(v.x * L2E);
        E[r][c + 1] = __builtin_amdgcn_exp2f(v.y * L2E);
        E[r][c + 2] = __builtin_amdgcn_exp2f(v.z * L2E);
        E[r][c + 3] = __builtin_amdgcn_exp2f(v.w * L2E);
      }
    }
  }

  if (tid == 0) giveup = 0;

  double Racc = 0.0;  // running log2-offset sum; identical on all threads

  for (int t = 1; t <= T_STEPS; ++t) {
    const int sprev = (t - 1) & (RING - 1);
    const int scur  = t & (RING - 1);
    const float* pprev = pring + sprev * NTAGS;

    __syncthreads();            // stage reusable; giveup visible

    if (giveup) break;

    // ---- poll + load p_{t-1}: values ARE the flags (NaN = not yet written)
    float pv[8];
    #pragma unroll
    for (int i = 0; i < 8; ++i) pv[i] = ld_agent(&pprev[tid + 512 * i]);
    {
      int rounds = 0;
      for (;;) {
        bool bad = false;
        #pragma unroll
        for (int i = 0; i < 8; ++i) bad |= (pv[i] != pv[i]);
        if (__ballot(bad) == 0ull) break;
        if (++rounds > (1 << 18)) { giveup = 1; break; }  // fail loud, not hang
        __builtin_amdgcn_s_sleep(1);
        #pragma unroll
        for (int i = 0; i < 8; ++i)
          if (pv[i] != pv[i]) pv[i] = ld_agent(&pprev[tid + 512 * i]);
      }
    }

    // ---- recycle slot t-2 to NaN. Safe: seeing full p_{t-1} implies every
    // wave passed its step-(t-1) poll of slot t-2 (skew <= 1 step).
    if (t >= 2 && wave == 0 && lane < 16)
      st_agent(&pring[((t - 2) & (RING - 1)) * NTAGS + g * 16 + lane],
               __builtin_nanf(""));

    // ---- stage p into LDS, track block max (= 2^(M_{t-1} - M_{t-2}))
    float mloc = 0.0f;  // p >= 0
    #pragma unroll
    for (int i = 0; i < 8; ++i) {
      const int f = tid + 512 * i;
      stage[f + 4 * (f >> 6)] = pv[i];
      mloc = fmaxf(mloc, pv[i]);
    }
    #pragma unroll
    for (int d = 32; d; d >>= 1) mloc = fmaxf(mloc, __shfl_xor(mloc, d, 64));
    if (lane == 0) wmax[wave] = mloc;

    // feats for my 2 rows (read-only input, normal cached loads)
    float fe[2];
    #pragma unroll
    for (int r = 0; r < 2; ++r) {
      const int tag = tagbase + r;
      const int fi = (tag == 0) ? 0 : tag - 1;
      fe[r] = feats[(size_t)(t - 1) * NRULES + fi] * L2E;
    }

    __syncthreads();

    if (giveup) break;

    float pmax = wmax[0];
    #pragma unroll
    for (int i = 1; i < 8; ++i) pmax = fmaxf(pmax, wmax[i]);
    const float rprev = __builtin_amdgcn_logf(pmax);   // log2(max p_{t-1})
    Racc += (double)rprev;

    // ---- matvec: a_r = sum_j E[r][j] * p[j] over this lane's 64 columns
    float a0 = 0.f, a1 = 0.f;
    const float* myp = stage + 68 * lane;
    #pragma unroll
    for (int k = 0; k < 16; ++k) {
      const float4 q = *reinterpret_cast<const float4*>(myp + 4 * k);
      a0 += E[0][4*k+0]*q.x; a1 += E[1][4*k+0]*q.x;
      a0 += E[0][4*k+1]*q.y; a1 += E[1][4*k+1]*q.y;
      a0 += E[0][4*k+2]*q.z; a1 += E[1][4*k+2]*q.z;
      a0 += E[0][4*k+3]*q.w; a1 += E[1][4*k+3]*q.w;
    }
    #pragma unroll
    for (int d = 32; d; d >>= 1) {
      a0 += __shfl_xor(a0, d, 64);
      a1 += __shfl_xor(a1, d, 64);
    }

    // y = acc_t - M_{t-1} in log2 domain; publish p_t = 2^y
    const float y0 = fe[0] + __builtin_amdgcn_logf(a0) - rprev;
    const float y1 = fe[1] + __builtin_amdgcn_logf(a1) - rprev;

    if (lane < 2) {
      const float y = (lane == 0) ? y0 : y1;
      st_agent(&pring[scur * NTAGS + tagbase + lane], __builtin_amdgcn_exp2f(y));
    }
  }

  // ---- finalization: Z = ln2 * (log2(sum p_T) + M_{T-1}); out = Z - logprob
  if (g == 0) {
    const float* pT = pring + (T_STEPS & (RING - 1)) * NTAGS;
    float pv[8];
    #pragma unroll
    for (int i = 0; i < 8; ++i) pv[i] = ld_agent(&pT[tid + 512 * i]);
    {
      int rounds = 0;
      for (;;) {
        bool bad = false;
        #pragma unroll
        for (int i = 0; i < 8; ++i) bad |= (pv[i] != pv[i]);
        if (__ballot(bad) == 0ull) break;
        if (++rounds > (1 << 18)) break;
        __builtin_amdgcn_s_sleep(1);
        #pragma unroll
        for (int i = 0; i < 8; ++i)
          if (pv[i] != pv[i]) pv[i] = ld_agent(&pT[tid + 512 * i]);
      }
    }
    float s = 0.f;
    #pragma unroll
    for (int i = 0; i < 8; ++i) s += pv[i];
    #pragma unroll
    for (int d = 32; d; d >>= 1) s += __shfl_xor(s, d, 64);
    __syncthreads();
    if (lane == 0) wmax[wave] = s;
    __syncthreads();
    if (tid == 0) {
      float tot = 0.f;
      #pragma unroll
      for (int i = 0; i < 8; ++i) tot += wmax[i];
      const double Z2 = (double)__builtin_amdgcn_logf(tot) + Racc;
      out[0] = (float)(LN2 * Z2 - (double)lp[0]);
    }
  }
}

extern "C" void kernel_launch(void* const* d_in, const int* in_sizes, int n_in,
                              void* d_out, int out_size, void* d_ws, size_t ws_size,
                              hipStream_t stream) {
  const float* feats = (const float*)d_in[0];   // (1024, 1, 4095) f32
  const float* trans = (const float*)d_in[1];   // (4096, 4096) f32
  const int*   tags  = (const int*)d_in[2];     // (1024,) i32
  float* out   = (float*)d_out;                 // (1,) f32
  float* pring = (float*)d_ws;                  // RING * NTAGS floats
  float* lp    = pring + RING * NTAGS;          // 1 float

  crf_init<<<64, 256, 0, stream>>>(pring);
  crf_logprob<<<1, 1024, 0, stream>>>(feats, trans, tags, lp);
  crf_scan<<<256, 512, 0, stream>>>(feats, trans, pring, lp, out);
}

// Round 3
// 4771.027 us; speedup vs baseline: 1.1382x; 1.0267x over previous
//
#include <hip/hip_runtime.h>

// CRF forward algorithm on MI355X.
// Linear-domain recurrence v_t = diag(2^feat) * (E @ v_{t-1}) with
// E = exp(transitions) held in VGPRs across 256 persistent blocks.
// Round 3 change: E0[64]/E1[64] with ALL accesses macro-expanded to literal
// constant indices. Rounds 1-2 spilled E to scratch (VGPR=176/96) because
// SROA runs before unrolling -> loop-variable GEPs were unpromotable, and the
// run was L3-BW-bound on scratch reloads (68GB / 5ms = 13.7 TB/s = L3 ceiling).
// Per step only the 4096-float state crosses blocks, synchronized by
// NaN-sentinel polling on an 8-slot ring (agent-scope ld/st bypass the
// non-coherent per-XCD L2s).

#define T_STEPS 1024
#define NRULES  4095
#define NTAGS   4096
#define RING    8
#define L2E     1.4426950408889634f
#define LN2     0.69314718055994530942

__device__ __forceinline__ float ld_agent(const float* p) {
  return __hip_atomic_load(p, __ATOMIC_RELAXED, __HIP_MEMORY_SCOPE_AGENT);
}
__device__ __forceinline__ void st_agent(float* p, float v) {
  __hip_atomic_store(p, v, __ATOMIC_RELAXED, __HIP_MEMORY_SCOPE_AGENT);
}

// Ring init: slot 0 = p_0 = [1, 0, 0, ...] (START state), slots 1..7 = NaN.
__global__ void crf_init(float* __restrict__ pring) {
  const float NANF = __builtin_nanf("");
  int idx = blockIdx.x * blockDim.x + threadIdx.x;
  int stride = gridDim.x * blockDim.x;
  for (int i = idx; i < RING * NTAGS; i += stride) {
    int slot = i >> 12;
    float v = (slot == 0) ? ((i == 0) ? 1.0f : 0.0f) : NANF;
    st_agent(&pring[i], v);
  }
}

// Supervised path: sum of emit + transition scores along the given tag path.
__global__ void crf_logprob(const float* __restrict__ feats,
                            const float* __restrict__ trans,
                            const int* __restrict__ tags,
                            float* __restrict__ lp) {
  int t = threadIdx.x;  // 1024 threads, one per step
  int prev = (t == 0) ? 0 : tags[t - 1];
  int nxt  = tags[t];
  int er = prev - 1; if (er < 0) er += NRULES;   // (prev-1) mod NRULES
  float v = feats[(size_t)t * NRULES + er] + trans[(size_t)nxt * NTAGS + prev];
  #pragma unroll
  for (int d = 32; d; d >>= 1) v += __shfl_xor(v, d, 64);
  __shared__ float sb[16];
  if ((t & 63) == 0) sb[t >> 6] = v;
  __syncthreads();
  if (t == 0) {
    float s = 0.f;
    #pragma unroll
    for (int i = 0; i < 16; ++i) s += sb[i];
    lp[0] = s;
  }
}

// Persistent scan. Grid 256 x block 512 (8 waves). Wave w of block g owns
// tags [g*16 + 2w, g*16 + 2w + 2); lane l owns columns [64l, 64l+64).
// tag 0 (START): transitions[0][:] = -1e4, so exp2(-1e4*L2E) underflows to
// +0.0f exactly -> E row 0 is all-zero from the data; p[0] stays 0 forever.
__launch_bounds__(512, 2)
__global__ void crf_scan(const float* __restrict__ feats,
                         const float* __restrict__ trans,
                         float* __restrict__ pring,
                         const float* __restrict__ lp,
                         float* __restrict__ out)
{
  const int g    = blockIdx.x;
  const int tid  = threadIdx.x;
  const int wave = tid >> 6;
  const int lane = tid & 63;
  const int tagbase = g * 16 + wave * 2;

  // p staged with +4 floats of pad per 64 so each lane's 64-float run starts
  // at float index 68*lane (byte 272*lane, 16B aligned, banks spread).
  __shared__ __align__(16) float stage[4352];
  __shared__ float wmax[8];
  __shared__ int giveup;

  // ---- one-time: E{0,1}[c] = exp(transitions[tag][64*lane + c]) ----
  // Literal-constant indices ONLY (macro-expanded) so early SROA promotes the
  // arrays to 128 SSA floats -> VGPRs, no scratch.
  float E0[64], E1[64];
  {
    const float* rp0 = trans + (size_t)(tagbase + 0) * NTAGS + lane * 64;
    const float* rp1 = trans + (size_t)(tagbase + 1) * NTAGS + lane * 64;
#define LDE(R, K) do {                                                  \
    const float4 v_ = *reinterpret_cast<const float4*>(rp##R + 4*(K));  \
    E##R[4*(K)+0] = __builtin_amdgcn_exp2f(v_.x * L2E);                 \
    E##R[4*(K)+1] = __builtin_amdgcn_exp2f(v_.y * L2E);                 \
    E##R[4*(K)+2] = __builtin_amdgcn_exp2f(v_.z * L2E);                 \
    E##R[4*(K)+3] = __builtin_amdgcn_exp2f(v_.w * L2E);                 \
  } while (0)
    LDE(0,0);  LDE(0,1);  LDE(0,2);  LDE(0,3);
    LDE(0,4);  LDE(0,5);  LDE(0,6);  LDE(0,7);
    LDE(0,8);  LDE(0,9);  LDE(0,10); LDE(0,11);
    LDE(0,12); LDE(0,13); LDE(0,14); LDE(0,15);
    LDE(1,0);  LDE(1,1);  LDE(1,2);  LDE(1,3);
    LDE(1,4);  LDE(1,5);  LDE(1,6);  LDE(1,7);
    LDE(1,8);  LDE(1,9);  LDE(1,10); LDE(1,11);
    LDE(1,12); LDE(1,13); LDE(1,14); LDE(1,15);
#undef LDE
  }

  if (tid == 0) giveup = 0;

  double Racc = 0.0;  // running log2-offset sum; identical on all threads

  for (int t = 1; t <= T_STEPS; ++t) {
    const int sprev = (t - 1) & (RING - 1);
    const int scur  = t & (RING - 1);
    const float* pprev = pring + sprev * NTAGS;

    __syncthreads();            // stage reusable; giveup visible

    if (giveup) break;

    // ---- poll + load p_{t-1}: values ARE the flags (NaN = not yet written)
    float pv[8];
    #pragma unroll
    for (int i = 0; i < 8; ++i) pv[i] = ld_agent(&pprev[tid + 512 * i]);
    {
      int rounds = 0;
      for (;;) {
        bool bad = false;
        #pragma unroll
        for (int i = 0; i < 8; ++i) bad |= (pv[i] != pv[i]);
        if (__ballot(bad) == 0ull) break;
        if (++rounds > (1 << 18)) { giveup = 1; break; }  // fail loud, not hang
        __builtin_amdgcn_s_sleep(1);
        #pragma unroll
        for (int i = 0; i < 8; ++i)
          if (pv[i] != pv[i]) pv[i] = ld_agent(&pprev[tid + 512 * i]);
      }
    }

    // ---- recycle slot t-2 to NaN. Safe: seeing full p_{t-1} implies every
    // wave passed its step-(t-1) poll of slot t-2 (skew <= 1 step).
    if (t >= 2 && wave == 0 && lane < 16)
      st_agent(&pring[((t - 2) & (RING - 1)) * NTAGS + g * 16 + lane],
               __builtin_nanf(""));

    // ---- stage p into LDS, track block max (= 2^(M_{t-1} - M_{t-2}))
    float mloc = 0.0f;  // p >= 0
    #pragma unroll
    for (int i = 0; i < 8; ++i) {
      const int f = tid + 512 * i;
      stage[f + 4 * (f >> 6)] = pv[i];
      mloc = fmaxf(mloc, pv[i]);
    }
    #pragma unroll
    for (int d = 32; d; d >>= 1) mloc = fmaxf(mloc, __shfl_xor(mloc, d, 64));
    if (lane == 0) wmax[wave] = mloc;

    // feats for my 2 rows (read-only input, normal cached loads)
    const int fi0 = (tagbase == 0) ? 0 : tagbase - 1;
    const float fe0 = feats[(size_t)(t - 1) * NRULES + fi0] * L2E;
    const float fe1 = feats[(size_t)(t - 1) * NRULES + tagbase] * L2E;

    __syncthreads();

    if (giveup) break;

    float pmax = wmax[0];
    #pragma unroll
    for (int i = 1; i < 8; ++i) pmax = fmaxf(pmax, wmax[i]);
    const float rprev = __builtin_amdgcn_logf(pmax);   // log2(max p_{t-1})
    Racc += (double)rprev;

    // ---- matvec: a_r = sum_j E_r[j] * p[j] over this lane's 64 columns
    float a0 = 0.f, a1 = 0.f;
    const float* myp = stage + 68 * lane;
#define MAC4(K) do {                                                     \
    const float4 q_ = *reinterpret_cast<const float4*>(myp + 4*(K));     \
    a0 = fmaf(E0[4*(K)+0], q_.x, a0); a1 = fmaf(E1[4*(K)+0], q_.x, a1);  \
    a0 = fmaf(E0[4*(K)+1], q_.y, a0); a1 = fmaf(E1[4*(K)+1], q_.y, a1);  \
    a0 = fmaf(E0[4*(K)+2], q_.z, a0); a1 = fmaf(E1[4*(K)+2], q_.z, a1);  \
    a0 = fmaf(E0[4*(K)+3], q_.w, a0); a1 = fmaf(E1[4*(K)+3], q_.w, a1);  \
  } while (0)
    MAC4(0);  MAC4(1);  MAC4(2);  MAC4(3);
    MAC4(4);  MAC4(5);  MAC4(6);  MAC4(7);
    MAC4(8);  MAC4(9);  MAC4(10); MAC4(11);
    MAC4(12); MAC4(13); MAC4(14); MAC4(15);
#undef MAC4
    #pragma unroll
    for (int d = 32; d; d >>= 1) {
      a0 += __shfl_xor(a0, d, 64);
      a1 += __shfl_xor(a1, d, 64);
    }

    // y = acc_t - M_{t-1} in log2 domain; publish p_t = 2^y
    const float y0 = fe0 + __builtin_amdgcn_logf(a0) - rprev;
    const float y1 = fe1 + __builtin_amdgcn_logf(a1) - rprev;

    if (lane < 2) {
      const float y = (lane == 0) ? y0 : y1;
      st_agent(&pring[scur * NTAGS + tagbase + lane], __builtin_amdgcn_exp2f(y));
    }
  }

  // ---- finalization: Z = ln2 * (log2(sum p_T) + M_{T-1}); out = Z - logprob
  if (g == 0) {
    const float* pT = pring + (T_STEPS & (RING - 1)) * NTAGS;
    float pv[8];
    #pragma unroll
    for (int i = 0; i < 8; ++i) pv[i] = ld_agent(&pT[tid + 512 * i]);
    {
      int rounds = 0;
      for (;;) {
        bool bad = false;
        #pragma unroll
        for (int i = 0; i < 8; ++i) bad |= (pv[i] != pv[i]);
        if (__ballot(bad) == 0ull) break;
        if (++rounds > (1 << 18)) break;
        __builtin_amdgcn_s_sleep(1);
        #pragma unroll
        for (int i = 0; i < 8; ++i)
          if (pv[i] != pv[i]) pv[i] = ld_agent(&pT[tid + 512 * i]);
      }
    }
    float s = 0.f;
    #pragma unroll
    for (int i = 0; i < 8; ++i) s += pv[i];
    #pragma unroll
    for (int d = 32; d; d >>= 1) s += __shfl_xor(s, d, 64);
    __syncthreads();
    if (lane == 0) wmax[wave] = s;
    __syncthreads();
    if (tid == 0) {
      float tot = 0.f;
      #pragma unroll
      for (int i = 0; i < 8; ++i) tot += wmax[i];
      const double Z2 = (double)__builtin_amdgcn_logf(tot) + Racc;
      out[0] = (float)(LN2 * Z2 - (double)lp[0]);
    }
  }
}

extern "C" void kernel_launch(void* const* d_in, const int* in_sizes, int n_in,
                              void* d_out, int out_size, void* d_ws, size_t ws_size,
                              hipStream_t stream) {
  const float* feats = (const float*)d_in[0];   // (1024, 1, 4095) f32
  const float* trans = (const float*)d_in[1];   // (4096, 4096) f32
  const int*   tags  = (const int*)d_in[2];     // (1024,) i32
  float* out   = (float*)d_out;                 // (1,) f32
  float* pring = (float*)d_ws;                  // RING * NTAGS floats
  float* lp    = pring + RING * NTAGS;          // 1 float

  crf_init<<<64, 256, 0, stream>>>(pring);
  crf_logprob<<<1, 1024, 0, stream>>>(feats, trans, tags, lp);
  crf_scan<<<256, 512, 0, stream>>>(feats, trans, pring, lp, out);
}